// Round 18
// baseline (671.562 us; speedup 1.0000x reference)
//
#include <hip/hip_runtime.h>

// ---------------- problem constants ----------------
#define HH 50
#define WW2 76
#define NPIX 3800
#define CIN 512
#define NANCH 34200     // 3800*9
#define NPRE 6000
#define NPOST 300
#define WPR 94          // ceil(6000/64) words per mask row

typedef unsigned long long u64;
typedef unsigned int u32;

// padded LDS index for u64 bitonic arrays: breaks pow2-stride bank conflicts
__device__ __forceinline__ int PADL(int i) { return i + (i >> 4); }

// ---------------- weight transposes + zero hist/info ----------------
template <bool DOW>
__global__ __launch_bounds__(256) void rpn_wtrans(const float* __restrict__ wgt,
                                                  float* __restrict__ wt,
                                                  const float* __restrict__ sw,
                                                  const float* __restrict__ lw,
                                                  float* __restrict__ wt2,
                                                  u32* __restrict__ hist,
                                                  u32* __restrict__ info) {
    __shared__ float tile[32][33];
    const int bx = blockIdx.x;          // cit tile (4608/32 = 144)
    const int by = blockIdx.y;          // ko  tile (512/32  = 16)
    const int t  = threadIdx.x;
    const int tx = t & 31, ty = t >> 5;
    int gid = (by * 144 + bx) * 256 + t;
    if (gid < 65536) hist[gid] = 0u;
    else if (gid < 65552) info[gid - 65536] = 0u;
    if (gid < 32768) {   // head weight pack: [c>>2][n][c&3]
        int c = gid >> 6, n = gid & 63;
        float v = 0.f;
        if (n < 18) v = sw[n * 512 + c];
        else if (n < 54) v = lw[(n - 18) * 512 + c];
        wt2[((c >> 2) * 64 + n) * 4 + (c & 3)] = v;
    }
    if (!DOW) return;
#pragma unroll
    for (int r = 0; r < 32; r += 8) {
        int ko = by * 32 + ty + r;
        tile[ty + r][tx] = wgt[(size_t)ko * 4608 + bx * 32 + tx];
    }
    __syncthreads();
#pragma unroll
    for (int r = 0; r < 32; r += 8) {
        int cit = bx * 32 + ty + r;
        wt[(size_t)cit * 512 + by * 32 + tx] = tile[tx][ty + r];
    }
}

// ---------------- conv1 v3: 4 outch/thread, transposed output ----------
// Proven 283-286us @ VGPR 96. Conv is a demonstrated local minimum; do not touch.
template <bool USEWT>
__global__ __launch_bounds__(256, 2) void rpn_conv1(
    const float* __restrict__ feat, const float* __restrict__ wsrc,
    float* __restrict__ Xpt, int cin_blk, int czbase) {
    const int yb = blockIdx.x;          // 13 row-quads
    const int kg = blockIdx.y;          // 8 groups of 64 outch
    const int cz = blockIdx.z + czbase; // nz split-K
    const int t  = threadIdx.x;
    const int kp = t & 15;
    const int ty = t >> 4;
    const int row  = ty >> 2;
    const int xseg = ty & 3;
    const int x0 = xseg * 19;
    __shared__ float in_l[2048];        // 4c*6r*84 = 2016 used
    __shared__ float w_l[2304];         // 4c*9tap*64ko, 9 chunks of 256

    const int y0 = yb * 4 - 1;
    int inSrc[8]; u32 inValid = 0, inPad = 0;
#pragma unroll
    for (int k = 0; k < 8; ++k) {
        int q = t + k * 256;
        int c = q / 504, rem = q - c * 504;      // 6r*84 = 504
        int r = rem / 84, xx = rem - r * 84;
        int gy = y0 + r, gx = xx - 1;
        bool inb = q < 2016;
        bool ok = inb && ((unsigned)gy < 50u) && ((unsigned)gx < 76u);
        inSrc[k] = c * NPIX + gy * 76 + gx;
        if (ok) inValid |= (1u << k);
        else if (inb) inPad |= (1u << k);
    }
#pragma unroll
    for (int k = 0; k < 8; ++k)
        if ((inPad >> k) & 1) in_l[t + k * 256] = 0.f;   // zero-pad once

    const float* wb;
    int wOffA = 0;
    int wSrc[9];
    if (USEWT) {
        wb = wsrc + (size_t)(cz * cin_blk) * 9 * 512 + kg * 64;
        wOffA = 8 * t - 7 * (t & 63);   // = 512*(t>>6) + (t&63)
    } else {
        wb = wsrc + (size_t)(kg * 64) * 4608 + (size_t)(cz * cin_blk) * 9;
#pragma unroll
        for (int k = 0; k < 9; ++k) {
            int q = t + k * 256;
            int c = q / 576, r2 = q - c * 576;
            int tap = r2 >> 6, ko = r2 & 63;
            wSrc[k] = ko * 4608 + c * 9 + tap;
        }
    }

    const float* fb = feat + (size_t)(cz * cin_blk) * NPIX;
    float acc[4][19];
#pragma unroll
    for (int o = 0; o < 4; ++o)
#pragma unroll
        for (int p = 0; p < 19; ++p) acc[o][p] = 0.f;

    const int niter = cin_blk >> 2;
#pragma unroll 1
    for (int it = 0; it < niter; ++it) {
        __syncthreads();
#pragma unroll
        for (int k = 0; k < 8; ++k)
            if ((inValid >> k) & 1) in_l[t + k * 256] = fb[inSrc[k]];
        if (USEWT) {
#pragma unroll
            for (int k = 0; k < 9; ++k)
                w_l[t + k * 256] = wb[wOffA + k * 2048];
        } else {
#pragma unroll
            for (int k = 0; k < 9; ++k)
                w_l[t + k * 256] = wb[wSrc[k]];
        }
        __syncthreads();
#pragma unroll 1
        for (int c = 0; c < 4; ++c) {
            const float* ir0 = &in_l[(c * 6 + row) * 84 + x0];
            const float* wl  = &w_l[c * 576 + 4 * kp];
#pragma unroll
            for (int r = 0; r < 3; ++r) {
                const float* ir = ir0 + r * 84;
                float win[21];
#pragma unroll
                for (int w = 0; w < 21; ++w) win[w] = ir[w];
                float wv[4][3];
#pragma unroll
                for (int tp = 0; tp < 3; ++tp) {
                    const float* wr = wl + (r * 3 + tp) * 64;
#pragma unroll
                    for (int o = 0; o < 4; ++o) wv[o][tp] = wr[o];
                }
#pragma unroll
                for (int p = 0; p < 19; ++p) {
#pragma unroll
                    for (int o = 0; o < 4; ++o) {
                        acc[o][p] = fmaf(wv[o][0], win[p],     acc[o][p]);
                        acc[o][p] = fmaf(wv[o][1], win[p + 1], acc[o][p]);
                        acc[o][p] = fmaf(wv[o][2], win[p + 2], acc[o][p]);
                    }
                }
            }
        }
        fb += 4 * NPIX;
        wb += USEWT ? 4 * 9 * 512 : 36;
    }

    const int k0 = kg * 64 + 4 * kp;
    const int y = yb * 4 + row;
    if (y < 50) {
        float* d0 = Xpt + ((size_t)cz * NPIX + y * 76 + x0) * 512 + k0;
#pragma unroll
        for (int p = 0; p < 19; ++p)
            *reinterpret_cast<float4*>(d0 + (size_t)p * 512) =
                make_float4(acc[0][p], acc[1][p], acc[2][p], acc[3][p]);
    }
}

// ---------------- head v2: 256 thr (4 waves), absorbs reduce + bias + relu --------
__global__ __launch_bounds__(256) void rpn_head(
    const float* __restrict__ Xpt, const float* __restrict__ wt2,
    const float* __restrict__ b1,
    const float* __restrict__ sb, const float* __restrict__ lb,
    const int* __restrict__ ihp, const int* __restrict__ iwp,
    float* __restrict__ out, float* __restrict__ boxes,
    u32* __restrict__ keys, u32* __restrict__ hist, int nz) {
    const int p0 = blockIdx.x * 8;     // 475 blocks x 8 px = 3800
    const int t  = threadIdx.x;
    __shared__ __align__(16) float xs[8 * 512];
    __shared__ float ovl[8][64];
    float4* dst = reinterpret_cast<float4*>(xs);
#pragma unroll
    for (int i = 0; i < 4; ++i) {
        int idx = t + i * 256;          // float4 index in 8*128
        int px = idx >> 7, cc = idx & 127;
        float4 v = *reinterpret_cast<const float4*>(b1 + cc * 4);
        const float* src = Xpt + ((size_t)(p0 + px)) * 512 + cc * 4;
        for (int z = 0; z < nz; ++z) {
            float4 x = *reinterpret_cast<const float4*>(src + (size_t)z * NPIX * 512);
            v.x += x.x; v.y += x.y; v.z += x.z; v.w += x.w;
        }
        v.x = fmaxf(v.x, 0.f); v.y = fmaxf(v.y, 0.f);
        v.z = fmaxf(v.z, 0.f); v.w = fmaxf(v.w, 0.f);
        dst[idx] = v;
    }
    __syncthreads();
    const int w = t >> 6, lane = t & 63;
    float a0, a1;
    {
        float b = (lane < 18) ? sb[lane] : ((lane < 54) ? lb[lane - 18] : 0.f);
        a0 = b; a1 = b;
    }
    const float4* wv = reinterpret_cast<const float4*>(wt2) + lane;
    const float* x0b = xs + (2 * w) * 512;
    const float* x1b = xs + (2 * w + 1) * 512;
#pragma unroll 4
    for (int c4 = 0; c4 < 128; ++c4) {
        float4 wq = wv[c4 * 64];
        float4 xa = *reinterpret_cast<const float4*>(x0b + c4 * 4);
        float4 xb = *reinterpret_cast<const float4*>(x1b + c4 * 4);
        a0 = fmaf(wq.x, xa.x, a0); a0 = fmaf(wq.y, xa.y, a0);
        a0 = fmaf(wq.z, xa.z, a0); a0 = fmaf(wq.w, xa.w, a0);
        a1 = fmaf(wq.x, xb.x, a1); a1 = fmaf(wq.y, xb.y, a1);
        a1 = fmaf(wq.z, xb.z, a1); a1 = fmaf(wq.w, xb.w, a1);
    }
    if (lane < 54) { ovl[2 * w][lane] = a0; ovl[2 * w + 1][lane] = a1; }
    __syncthreads();
    if (t < 72) {
        const int px = t / 9, a = t - px * 9;
        const float ch = (float)(*ihp), cw = (float)(*iwp);
        const int p = p0 + px;
        const float* ov = ovl[px];
        const float s0 = ov[2 * a], s1 = ov[2 * a + 1];
        const float dy = ov[18 + 4 * a], dx = ov[18 + 4 * a + 1];
        const float dh = ov[18 + 4 * a + 2], dw = ov[18 + 4 * a + 3];
        const int yy = p / WW2, xx = p % WW2;
        const int ai = p * 9 + a;
        *reinterpret_cast<float4*>(out + ai * 4) = make_float4(dy, dx, dh, dw);
        *reinterpret_cast<float2*>(out + 136800 + ai * 2) = make_float2(s0, s1);
        double r  = (a < 3) ? 0.5 : (a < 6) ? 1.0 : 2.0;
        int m3 = a % 3;
        double s2 = (m3 == 0) ? 8.0 : (m3 == 1) ? 16.0 : 32.0;
        double hd = (16.0 * s2) * sqrt(r);
        double wd = (16.0 * s2) * sqrt(1.0 / r);
        float ay1 = (float)(8.0 - hd * 0.5), ax1 = (float)(8.0 - wd * 0.5);
        float ay2 = (float)(8.0 + hd * 0.5), ax2 = (float)(8.0 + wd * 0.5);
        float fy = (float)(yy * 16), fx = (float)(xx * 16);
        float A0 = ay1 + fy, A1 = ax1 + fx, A2 = ay2 + fy, A3 = ax2 + fx;
        *reinterpret_cast<float4*>(out + 206400 + ai * 4) = make_float4(A0, A1, A2, A3);
        float ah = __fsub_rn(A2, A0), aw = __fsub_rn(A3, A1);
        float cy = __fadd_rn(A0, __fmul_rn(0.5f, ah));
        float cx = __fadd_rn(A1, __fmul_rn(0.5f, aw));
        float ncy = __fadd_rn(__fmul_rn(dy, ah), cy);
        float ncx = __fadd_rn(__fmul_rn(dx, aw), cx);
        float nh = __fmul_rn(expf(dh), ah);
        float nw = __fmul_rn(expf(dw), aw);
        float b0 = __fsub_rn(ncy, __fmul_rn(0.5f, nh));
        float b1v = __fsub_rn(ncx, __fmul_rn(0.5f, nw));
        float b2 = __fadd_rn(ncy, __fmul_rn(0.5f, nh));
        float b3 = __fadd_rn(ncx, __fmul_rn(0.5f, nw));
        b0 = fminf(fmaxf(b0, 0.f), ch); b2 = fminf(fmaxf(b2, 0.f), ch);
        b1v = fminf(fmaxf(b1v, 0.f), cw); b3 = fminf(fmaxf(b3, 0.f), cw);
        float hs = __fsub_rn(b2, b0), wsz = __fsub_rn(b3, b1v);
        float m = fmaxf(s0, s1);
        float e0 = expf(__fsub_rn(s0, m)), e1 = expf(__fsub_rn(s1, m));
        float fg = __fdiv_rn(e1, __fadd_rn(e0, e1));
        float score = (hs >= 16.f && wsz >= 16.f) ? fg : -__builtin_inff();
        *reinterpret_cast<float4*>(boxes + ai * 4) = make_float4(b0, b1v, b2, b3);
        u32 kb = __float_as_uint(score);
        kb = (kb & 0x80000000u) ? ~kb : (kb | 0x80000000u);
        keys[ai] = kb;
        atomicAdd(&hist[kb >> 16], 1u);
    }
}

// ---------------- threshold bin: fully parallel suffix scans (1 block) ------------
__global__ __launch_bounds__(256) void rpn_thresh(const u32* __restrict__ hist,
                                                  u32* __restrict__ info) {
    __shared__ u32 part[256], h2[256];
    __shared__ int segs;
    const int t = threadIdx.x;
    u32 s = 0;
    const u32* hp = hist + t * 256;
    for (int b = 0; b < 256; ++b) s += hp[b];
    part[t] = s;
    __syncthreads();
    for (int off = 1; off < 256; off <<= 1) {
        u32 v = part[t];
        u32 add = (t + off < 256) ? part[t + off] : 0u;
        __syncthreads();
        part[t] = v + add;
        __syncthreads();
    }
    u32 suf  = part[t];
    u32 sufn = (t < 255) ? part[t + 1] : 0u;
    if (suf >= NPRE && sufn < NPRE) segs = t;
    __syncthreads();
    const int seg = segs;
    const u32 above = (seg < 255) ? part[seg + 1] : 0u;
    h2[t] = hist[seg * 256 + t];
    __syncthreads();
    for (int off = 1; off < 256; off <<= 1) {
        u32 v = h2[t];
        u32 add = (t + off < 256) ? h2[t + off] : 0u;
        __syncthreads();
        h2[t] = v + add;
        __syncthreads();
    }
    u32 tot  = above + h2[t];
    u32 totn = above + ((t < 255) ? h2[t + 1] : 0u);
    if (tot >= NPRE && totn < NPRE) info[0] = (u32)(seg * 256 + t);
}

// ---------------- select candidates (bin >= T), per-wave ballot compaction --------
__global__ void rpn_select(const u32* __restrict__ keys, u32* __restrict__ info,
                           u64* __restrict__ selk) {
    const int idx = blockIdx.x * 256 + threadIdx.x;
    const int lane = threadIdx.x & 63;
    u32 k = (idx < NANCH) ? keys[idx] : 0u;
    bool sel = (idx < NANCH) && ((k >> 16) >= info[0]);
    u64 ball = __ballot(sel);
    u32 base = 0;
    if (lane == 0 && ball) base = atomicAdd(&info[2], (u32)__popcll(ball));
    base = __shfl(base, 0);
    if (sel) {
        u32 pos = base + (u32)__popcll(ball & ((1ull << lane) - 1ull));
        if (pos < 8192) selk[pos] = ((u64)k << 32) | (u64)(0xFFFFFFFFu - (u32)idx);
    }
}

// ---------------- multi-block bitonic sort (padded LDS, spread over CUs) ----------
__global__ __launch_bounds__(1024) void rpn_sort_local(u64* __restrict__ selk,
                                                       const u32* __restrict__ info) {
    __shared__ u64 s[2176];     // 2048 + 2048/16 pad
    const int t = threadIdx.x;
    const int seg = blockIdx.x;
    const int base = seg * 2048;
    int n = (int)info[2]; if (n > 8192) n = 8192;
    for (int i = t; i < 2048; i += 1024)
        s[PADL(i)] = (base + i < n) ? selk[base + i] : 0ull;
    __syncthreads();
    const bool D = ((seg & 1) == 0);
    for (int k = 2; k <= 2048; k <<= 1) {
        for (int j = k >> 1; j > 0; j >>= 1) {
            int p1 = ((t & ~(j - 1)) << 1) | (t & (j - 1));
            int p2 = p1 | j;
            bool desc = (((p1 & k) == 0) == D);
            u64 A = s[PADL(p1)], B = s[PADL(p2)];
            if (desc ? (A < B) : (A > B)) { s[PADL(p1)] = B; s[PADL(p2)] = A; }
            __syncthreads();
        }
    }
    for (int i = t; i < 2048; i += 1024) selk[base + i] = s[PADL(i)];
}

__global__ __launch_bounds__(512) void rpn_sort_gpass(u64* __restrict__ selk,
                                                      int k, int j) {
    int i = blockIdx.x * 512 + threadIdx.x;
    int p1 = ((i & ~(j - 1)) << 1) | (i & (j - 1));
    int p2 = p1 | j;
    bool desc = ((p1 & k) == 0);
    u64 A = selk[p1], B = selk[p2];
    if (desc ? (A < B) : (A > B)) { selk[p1] = B; selk[p2] = A; }
}

template <bool FINAL>
__global__ __launch_bounds__(1024) void rpn_sort_lmerge(u64* __restrict__ selk, int k,
                                                        const float* __restrict__ boxes,
                                                        float* __restrict__ bk) {
    __shared__ u64 s[2176];
    const int t = threadIdx.x;
    const int base = blockIdx.x * 2048;
    for (int i = t; i < 2048; i += 1024) s[PADL(i)] = selk[base + i];
    __syncthreads();
    const bool desc = ((base & k) == 0);
    for (int j = 1024; j > 0; j >>= 1) {
        int p1 = ((t & ~(j - 1)) << 1) | (t & (j - 1));
        int p2 = p1 | j;
        u64 A = s[PADL(p1)], B = s[PADL(p2)];
        if (desc ? (A < B) : (A > B)) { s[PADL(p1)] = B; s[PADL(p2)] = A; }
        __syncthreads();
    }
    if (FINAL) {
        for (int i = t; i < 2048; i += 1024) {
            int r = base + i;
            if (r < NPRE) {
                u32 oi = 0xFFFFFFFFu - (u32)(s[PADL(i)] & 0xFFFFFFFFull);
                if (oi >= NANCH) oi = 0;
                reinterpret_cast<float4*>(bk)[r] = reinterpret_cast<const float4*>(boxes)[oi];
            }
        }
    } else {
        for (int i = t; i < 2048; i += 1024) selk[base + i] = s[PADL(i)];
    }
}

// ---------------- IoU bitmask: 4 waves/block share the jb tile ----------------
__global__ __launch_bounds__(256) void rpn_iou(const float* __restrict__ bk,
                                               u64* __restrict__ mask) {
    const int t = threadIdx.x;
    const int lane = t & 63, w = t >> 6;
    const int bj = blockIdx.x;
    const int bi = blockIdx.y * 4 + w;       // grid.y = 24 -> bi 0..95 (guard < 94)
    const int j0 = bj * 64;
    __shared__ float4 jb[64];
    if (t < 64) jb[t] = (j0 + t < NPRE) ? reinterpret_cast<const float4*>(bk)[j0 + t]
                                        : make_float4(0.f, 0.f, 0.f, 0.f);
    __syncthreads();
    if (bi >= WPR) return;
    const int i = bi * 64 + lane;
    if (j0 + 63 <= bi * 64) {                // wave-uniform: all pairs j <= i
        if (i < NPRE) mask[(size_t)i * WPR + bj] = 0ull;
        return;
    }
    if (i >= NPRE) return;
    float4 b = reinterpret_cast<const float4*>(bk)[i];
    float areai = __fmul_rn(__fsub_rn(b.z, b.x), __fsub_rn(b.w, b.y));
    u64 bits = 0ull;
    for (int jj = 0; jj < 64; ++jj) {
        int j = j0 + jj;
        if (j <= i || j >= NPRE) continue;
        float4 c = jb[jj];
        float ty = fmaxf(b.x, c.x), tx = fmaxf(b.y, c.y);
        float by = fminf(b.z, c.z), bx2 = fminf(b.w, c.w);
        float ih = fmaxf(__fsub_rn(by, ty), 0.f);
        float iw = fmaxf(__fsub_rn(bx2, tx), 0.f);
        float inter = __fmul_rn(ih, iw);
        float areaj = __fmul_rn(__fsub_rn(c.z, c.x), __fsub_rn(c.w, c.y));
        float denom = __fadd_rn(__fsub_rn(__fadd_rn(areai, areaj), inter), 1e-9f);
        float iou = __fdiv_rn(inter, denom);
        if (iou > 0.7f) bits |= (1ull << jj);
    }
    mask[(size_t)i * WPR + bj] = bits;
}

// ---------------- sequential greedy NMS: 64-deep prefetch (hides remote-L2/HBM) ---
// single wave, VGPR budget 512 via (64,1); 3x64 u64 prefetch regs, static indices.
__global__ __launch_bounds__(64, 1) void rpn_nms(const u64* __restrict__ mask,
                                                 const float* __restrict__ bk,
                                                 float* __restrict__ rois) {
    const int lane = threadIdx.x;
    u64 rem0 = 0ull, rem1 = 0ull, curW = 0ull;
    __shared__ unsigned short klist[304];
    int kcnt = 0;
    u64 pm0[64], pm1[64], pmg[64];
#pragma unroll
    for (int u = 0; u < 64; ++u) {
        pm0[u] = mask[(size_t)u * WPR + lane];
        pm1[u] = (lane < 30) ? mask[(size_t)u * WPR + 64 + lane] : 0ull;
        pmg[u] = mask[(size_t)u * WPR + (u >> 6)];
    }
    bool done = false;
    for (int base = 0; base < NPRE && !done; base += 64) {
        {
            int w = base >> 6;
            curW = (w < 64) ? __shfl(rem0, w) : __shfl(rem1, w - 64);
        }
#pragma unroll
        for (int u = 0; u < 64; ++u) {
            const int i = base + u;
            u64 m0 = pm0[u], m1 = pm1[u], mg = pmg[u];
            const int ni = i + 64;     // mask buffer has slack rows (to 6080)
            pm0[u] = mask[(size_t)ni * WPR + lane];
            pm1[u] = (lane < 30) ? mask[(size_t)ni * WPR + 64 + lane] : 0ull;
            pmg[u] = mask[(size_t)ni * WPR + (ni >> 6)];
            if (((curW >> (i & 63)) & 1ull) == 0ull) {
                rem0 |= m0;
                rem1 |= m1;
                curW |= mg;
                if (lane == 0 && kcnt < 304) klist[kcnt] = (unsigned short)i;
                ++kcnt;
                if (kcnt >= NPOST) { done = true; break; }
            }
        }
    }
    __syncthreads();
    const int nk = kcnt < NPOST ? kcnt : NPOST;
    for (int r = lane; r < nk; r += 64) {
        int bi = klist[r];
        reinterpret_cast<float4*>(rois)[r] = reinterpret_cast<const float4*>(bk)[bi];
    }
    if (kcnt < NPOST) {
        int pos = kcnt;
        for (int i = 0; i < NPRE && pos < NPOST; ++i) {
            int w = i >> 6;
            u64 wv = (w < 64) ? __shfl(rem0, w) : __shfl(rem1, w - 64);
            if ((wv >> (i & 63)) & 1ull) {
                if (lane < 4) rois[pos * 4 + lane] = bk[i * 4 + lane];
                ++pos;
            }
        }
    }
}

extern "C" void kernel_launch(void* const* d_in, const int* in_sizes, int n_in,
                              void* d_out, int out_size, void* d_ws, size_t ws_size,
                              hipStream_t stream) {
    (void)in_sizes; (void)n_in; (void)out_size;
    const float* feat = (const float*)d_in[0];
    const float* w1   = (const float*)d_in[1];
    const float* b1   = (const float*)d_in[2];
    const float* sw   = (const float*)d_in[3];
    const float* sb   = (const float*)d_in[4];
    const float* lw   = (const float*)d_in[5];
    const float* lb   = (const float*)d_in[6];
    const int*   ih   = (const int*)d_in[7];
    const int*   iw   = (const int*)d_in[8];
    float* out = (float*)d_out;

    const size_t WT_B    = 9437184;   // 512*512*9*4
    const size_t WT2_B   = 131072;    // 512*64*4
    const size_t MASK_B  = 4580000;   // >= 6080 rows x 94 words (64-deep nms prefetch slack)
    const size_t REST_B  = WT2_B + 547200 + 136800 + 262144 + 64 + 65536 + 96000 + MASK_B;
    const size_t SLICE_B = (size_t)512 * NPIX * 4;
    int nz; bool usewt;
    if      (ws_size >= 8 * SLICE_B + WT_B + REST_B) { nz = 8; usewt = true; }
    else if (ws_size >= 4 * SLICE_B + WT_B + REST_B) { nz = 4; usewt = true; }
    else if (ws_size >= 2 * SLICE_B + WT_B + REST_B) { nz = 2; usewt = true; }
    else                                             { nz = 2; usewt = false; }

    char* p = (char*)d_ws;
    float* Xpt = (float*)p;          p += (size_t)nz * SLICE_B;
    float* wt = nullptr;
    if (usewt) { wt = (float*)p;     p += WT_B; }
    float* wt2    = (float*)p;       p += WT2_B;
    float* boxes  = (float*)p;       p += 547200;
    u32*   keys   = (u32*)p;         p += 136800;
    u32*   hist   = (u32*)p;         p += 262144;
    u32*   info   = (u32*)p;         p += 64;
    u64*   selk   = (u64*)p;         p += 65536;
    float* bk     = (float*)p;       p += 96000;
    u64*   mask   = (u64*)p;

    const int cin_blk = 512 / nz;

    if (usewt) {
        rpn_wtrans<true><<<dim3(144, 16), 256, 0, stream>>>(w1, wt, sw, lw, wt2, hist, info);
        rpn_conv1<true><<<dim3(13, 8, nz), 256, 0, stream>>>(feat, wt, Xpt, cin_blk, 0);
    } else {
        rpn_wtrans<false><<<dim3(144, 16), 256, 0, stream>>>(w1, nullptr, sw, lw, wt2, hist, info);
        rpn_conv1<false><<<dim3(13, 8, nz), 256, 0, stream>>>(feat, w1, Xpt, cin_blk, 0);
    }
    rpn_head<<<475, 256, 0, stream>>>(Xpt, wt2, b1, sb, lb, ih, iw, out, boxes, keys, hist, nz);
    rpn_thresh<<<1, 256, 0, stream>>>(hist, info);
    rpn_select<<<(NANCH + 255) / 256, 256, 0, stream>>>(keys, info, selk);
    rpn_sort_local<<<4, 1024, 0, stream>>>(selk, info);
    rpn_sort_gpass<<<8, 512, 0, stream>>>(selk, 4096, 2048);
    rpn_sort_lmerge<false><<<4, 1024, 0, stream>>>(selk, 4096, nullptr, nullptr);
    rpn_sort_gpass<<<8, 512, 0, stream>>>(selk, 8192, 4096);
    rpn_sort_gpass<<<8, 512, 0, stream>>>(selk, 8192, 2048);
    rpn_sort_lmerge<true><<<4, 1024, 0, stream>>>(selk, 8192, boxes, bk);
    rpn_iou<<<dim3(WPR, 24), 256, 0, stream>>>(bk, mask);
    rpn_nms<<<1, 64, 0, stream>>>(mask, bk, out + 205200);
}

// Round 19
// 571.713 us; speedup vs baseline: 1.1746x; 1.1746x over previous
//
#include <hip/hip_runtime.h>

// ---------------- problem constants ----------------
#define HH 50
#define WW2 76
#define NPIX 3800
#define CIN 512
#define NANCH 34200     // 3800*9
#define NPRE 6000
#define NPOST 300
#define WPR 94          // ceil(6000/64) words per mask row

typedef unsigned long long u64;
typedef unsigned int u32;

// padded LDS index for u64 bitonic arrays: breaks pow2-stride bank conflicts
__device__ __forceinline__ int PADL(int i) { return i + (i >> 4); }

// ---------------- weight transposes + zero hist/info ----------------
template <bool DOW>
__global__ __launch_bounds__(256) void rpn_wtrans(const float* __restrict__ wgt,
                                                  float* __restrict__ wt,
                                                  const float* __restrict__ sw,
                                                  const float* __restrict__ lw,
                                                  float* __restrict__ wt2,
                                                  u32* __restrict__ hist,
                                                  u32* __restrict__ info) {
    __shared__ float tile[32][33];
    const int bx = blockIdx.x;          // cit tile (4608/32 = 144)
    const int by = blockIdx.y;          // ko  tile (512/32  = 16)
    const int t  = threadIdx.x;
    const int tx = t & 31, ty = t >> 5;
    int gid = (by * 144 + bx) * 256 + t;
    if (gid < 65536) hist[gid] = 0u;
    else if (gid < 65552) info[gid - 65536] = 0u;
    if (gid < 32768) {   // head weight pack: [c>>2][n][c&3]
        int c = gid >> 6, n = gid & 63;
        float v = 0.f;
        if (n < 18) v = sw[n * 512 + c];
        else if (n < 54) v = lw[(n - 18) * 512 + c];
        wt2[((c >> 2) * 64 + n) * 4 + (c & 3)] = v;
    }
    if (!DOW) return;
#pragma unroll
    for (int r = 0; r < 32; r += 8) {
        int ko = by * 32 + ty + r;
        tile[ty + r][tx] = wgt[(size_t)ko * 4608 + bx * 32 + tx];
    }
    __syncthreads();
#pragma unroll
    for (int r = 0; r < 32; r += 8) {
        int cit = bx * 32 + ty + r;
        wt[(size_t)cit * 512 + by * 32 + tx] = tile[tx][ty + r];
    }
}

// ---------------- conv1 v3: 4 outch/thread, transposed output ----------
// Proven 283-286us @ VGPR 96. Conv is a demonstrated local minimum (8 variants
// all 283-297). nms prefetch depth is bounded by vmcnt capacity (6-bit, max 63
// outstanding) — 64-deep refresh (r18) serialized and cost +96us. Do not touch.
template <bool USEWT>
__global__ __launch_bounds__(256, 2) void rpn_conv1(
    const float* __restrict__ feat, const float* __restrict__ wsrc,
    float* __restrict__ Xpt, int cin_blk, int czbase) {
    const int yb = blockIdx.x;          // 13 row-quads
    const int kg = blockIdx.y;          // 8 groups of 64 outch
    const int cz = blockIdx.z + czbase; // nz split-K
    const int t  = threadIdx.x;
    const int kp = t & 15;
    const int ty = t >> 4;
    const int row  = ty >> 2;
    const int xseg = ty & 3;
    const int x0 = xseg * 19;
    __shared__ float in_l[2048];        // 4c*6r*84 = 2016 used
    __shared__ float w_l[2304];         // 4c*9tap*64ko, 9 chunks of 256

    const int y0 = yb * 4 - 1;
    int inSrc[8]; u32 inValid = 0, inPad = 0;
#pragma unroll
    for (int k = 0; k < 8; ++k) {
        int q = t + k * 256;
        int c = q / 504, rem = q - c * 504;      // 6r*84 = 504
        int r = rem / 84, xx = rem - r * 84;
        int gy = y0 + r, gx = xx - 1;
        bool inb = q < 2016;
        bool ok = inb && ((unsigned)gy < 50u) && ((unsigned)gx < 76u);
        inSrc[k] = c * NPIX + gy * 76 + gx;
        if (ok) inValid |= (1u << k);
        else if (inb) inPad |= (1u << k);
    }
#pragma unroll
    for (int k = 0; k < 8; ++k)
        if ((inPad >> k) & 1) in_l[t + k * 256] = 0.f;   // zero-pad once

    const float* wb;
    int wOffA = 0;
    int wSrc[9];
    if (USEWT) {
        wb = wsrc + (size_t)(cz * cin_blk) * 9 * 512 + kg * 64;
        wOffA = 8 * t - 7 * (t & 63);   // = 512*(t>>6) + (t&63)
    } else {
        wb = wsrc + (size_t)(kg * 64) * 4608 + (size_t)(cz * cin_blk) * 9;
#pragma unroll
        for (int k = 0; k < 9; ++k) {
            int q = t + k * 256;
            int c = q / 576, r2 = q - c * 576;
            int tap = r2 >> 6, ko = r2 & 63;
            wSrc[k] = ko * 4608 + c * 9 + tap;
        }
    }

    const float* fb = feat + (size_t)(cz * cin_blk) * NPIX;
    float acc[4][19];
#pragma unroll
    for (int o = 0; o < 4; ++o)
#pragma unroll
        for (int p = 0; p < 19; ++p) acc[o][p] = 0.f;

    const int niter = cin_blk >> 2;
#pragma unroll 1
    for (int it = 0; it < niter; ++it) {
        __syncthreads();
#pragma unroll
        for (int k = 0; k < 8; ++k)
            if ((inValid >> k) & 1) in_l[t + k * 256] = fb[inSrc[k]];
        if (USEWT) {
#pragma unroll
            for (int k = 0; k < 9; ++k)
                w_l[t + k * 256] = wb[wOffA + k * 2048];
        } else {
#pragma unroll
            for (int k = 0; k < 9; ++k)
                w_l[t + k * 256] = wb[wSrc[k]];
        }
        __syncthreads();
#pragma unroll 1
        for (int c = 0; c < 4; ++c) {
            const float* ir0 = &in_l[(c * 6 + row) * 84 + x0];
            const float* wl  = &w_l[c * 576 + 4 * kp];
#pragma unroll
            for (int r = 0; r < 3; ++r) {
                const float* ir = ir0 + r * 84;
                float win[21];
#pragma unroll
                for (int w = 0; w < 21; ++w) win[w] = ir[w];
                float wv[4][3];
#pragma unroll
                for (int tp = 0; tp < 3; ++tp) {
                    const float* wr = wl + (r * 3 + tp) * 64;
#pragma unroll
                    for (int o = 0; o < 4; ++o) wv[o][tp] = wr[o];
                }
#pragma unroll
                for (int p = 0; p < 19; ++p) {
#pragma unroll
                    for (int o = 0; o < 4; ++o) {
                        acc[o][p] = fmaf(wv[o][0], win[p],     acc[o][p]);
                        acc[o][p] = fmaf(wv[o][1], win[p + 1], acc[o][p]);
                        acc[o][p] = fmaf(wv[o][2], win[p + 2], acc[o][p]);
                    }
                }
            }
        }
        fb += 4 * NPIX;
        wb += USEWT ? 4 * 9 * 512 : 36;
    }

    const int k0 = kg * 64 + 4 * kp;
    const int y = yb * 4 + row;
    if (y < 50) {
        float* d0 = Xpt + ((size_t)cz * NPIX + y * 76 + x0) * 512 + k0;
#pragma unroll
        for (int p = 0; p < 19; ++p)
            *reinterpret_cast<float4*>(d0 + (size_t)p * 512) =
                make_float4(acc[0][p], acc[1][p], acc[2][p], acc[3][p]);
    }
}

// ---------------- head v2: 256 thr (4 waves), absorbs reduce + bias + relu --------
// wave w owns px pair {2w, 2w+1}; lanes 0..53 compute both dot products.
__global__ __launch_bounds__(256) void rpn_head(
    const float* __restrict__ Xpt, const float* __restrict__ wt2,
    const float* __restrict__ b1,
    const float* __restrict__ sb, const float* __restrict__ lb,
    const int* __restrict__ ihp, const int* __restrict__ iwp,
    float* __restrict__ out, float* __restrict__ boxes,
    u32* __restrict__ keys, u32* __restrict__ hist, int nz) {
    const int p0 = blockIdx.x * 8;     // 475 blocks x 8 px = 3800
    const int t  = threadIdx.x;
    __shared__ __align__(16) float xs[8 * 512];
    __shared__ float ovl[8][64];
    float4* dst = reinterpret_cast<float4*>(xs);
#pragma unroll
    for (int i = 0; i < 4; ++i) {
        int idx = t + i * 256;          // float4 index in 8*128
        int px = idx >> 7, cc = idx & 127;
        float4 v = *reinterpret_cast<const float4*>(b1 + cc * 4);
        const float* src = Xpt + ((size_t)(p0 + px)) * 512 + cc * 4;
        for (int z = 0; z < nz; ++z) {
            float4 x = *reinterpret_cast<const float4*>(src + (size_t)z * NPIX * 512);
            v.x += x.x; v.y += x.y; v.z += x.z; v.w += x.w;
        }
        v.x = fmaxf(v.x, 0.f); v.y = fmaxf(v.y, 0.f);
        v.z = fmaxf(v.z, 0.f); v.w = fmaxf(v.w, 0.f);
        dst[idx] = v;
    }
    __syncthreads();
    const int w = t >> 6, lane = t & 63;
    float a0, a1;
    {
        float b = (lane < 18) ? sb[lane] : ((lane < 54) ? lb[lane - 18] : 0.f);
        a0 = b; a1 = b;
    }
    const float4* wv = reinterpret_cast<const float4*>(wt2) + lane;
    const float* x0b = xs + (2 * w) * 512;
    const float* x1b = xs + (2 * w + 1) * 512;
#pragma unroll 4
    for (int c4 = 0; c4 < 128; ++c4) {
        float4 wq = wv[c4 * 64];
        float4 xa = *reinterpret_cast<const float4*>(x0b + c4 * 4);
        float4 xb = *reinterpret_cast<const float4*>(x1b + c4 * 4);
        a0 = fmaf(wq.x, xa.x, a0); a0 = fmaf(wq.y, xa.y, a0);
        a0 = fmaf(wq.z, xa.z, a0); a0 = fmaf(wq.w, xa.w, a0);
        a1 = fmaf(wq.x, xb.x, a1); a1 = fmaf(wq.y, xb.y, a1);
        a1 = fmaf(wq.z, xb.z, a1); a1 = fmaf(wq.w, xb.w, a1);
    }
    if (lane < 54) { ovl[2 * w][lane] = a0; ovl[2 * w + 1][lane] = a1; }
    __syncthreads();
    if (t < 72) {
        const int px = t / 9, a = t - px * 9;
        const float ch = (float)(*ihp), cw = (float)(*iwp);
        const int p = p0 + px;
        const float* ov = ovl[px];
        const float s0 = ov[2 * a], s1 = ov[2 * a + 1];
        const float dy = ov[18 + 4 * a], dx = ov[18 + 4 * a + 1];
        const float dh = ov[18 + 4 * a + 2], dw = ov[18 + 4 * a + 3];
        const int yy = p / WW2, xx = p % WW2;
        const int ai = p * 9 + a;
        *reinterpret_cast<float4*>(out + ai * 4) = make_float4(dy, dx, dh, dw);
        *reinterpret_cast<float2*>(out + 136800 + ai * 2) = make_float2(s0, s1);
        double r  = (a < 3) ? 0.5 : (a < 6) ? 1.0 : 2.0;
        int m3 = a % 3;
        double s2 = (m3 == 0) ? 8.0 : (m3 == 1) ? 16.0 : 32.0;
        double hd = (16.0 * s2) * sqrt(r);
        double wd = (16.0 * s2) * sqrt(1.0 / r);
        float ay1 = (float)(8.0 - hd * 0.5), ax1 = (float)(8.0 - wd * 0.5);
        float ay2 = (float)(8.0 + hd * 0.5), ax2 = (float)(8.0 + wd * 0.5);
        float fy = (float)(yy * 16), fx = (float)(xx * 16);
        float A0 = ay1 + fy, A1 = ax1 + fx, A2 = ay2 + fy, A3 = ax2 + fx;
        *reinterpret_cast<float4*>(out + 206400 + ai * 4) = make_float4(A0, A1, A2, A3);
        float ah = __fsub_rn(A2, A0), aw = __fsub_rn(A3, A1);
        float cy = __fadd_rn(A0, __fmul_rn(0.5f, ah));
        float cx = __fadd_rn(A1, __fmul_rn(0.5f, aw));
        float ncy = __fadd_rn(__fmul_rn(dy, ah), cy);
        float ncx = __fadd_rn(__fmul_rn(dx, aw), cx);
        float nh = __fmul_rn(expf(dh), ah);
        float nw = __fmul_rn(expf(dw), aw);
        float b0 = __fsub_rn(ncy, __fmul_rn(0.5f, nh));
        float b1v = __fsub_rn(ncx, __fmul_rn(0.5f, nw));
        float b2 = __fadd_rn(ncy, __fmul_rn(0.5f, nh));
        float b3 = __fadd_rn(ncx, __fmul_rn(0.5f, nw));
        b0 = fminf(fmaxf(b0, 0.f), ch); b2 = fminf(fmaxf(b2, 0.f), ch);
        b1v = fminf(fmaxf(b1v, 0.f), cw); b3 = fminf(fmaxf(b3, 0.f), cw);
        float hs = __fsub_rn(b2, b0), wsz = __fsub_rn(b3, b1v);
        float m = fmaxf(s0, s1);
        float e0 = expf(__fsub_rn(s0, m)), e1 = expf(__fsub_rn(s1, m));
        float fg = __fdiv_rn(e1, __fadd_rn(e0, e1));
        float score = (hs >= 16.f && wsz >= 16.f) ? fg : -__builtin_inff();
        *reinterpret_cast<float4*>(boxes + ai * 4) = make_float4(b0, b1v, b2, b3);
        u32 kb = __float_as_uint(score);
        kb = (kb & 0x80000000u) ? ~kb : (kb | 0x80000000u);
        keys[ai] = kb;
        atomicAdd(&hist[kb >> 16], 1u);
    }
}

// ---------------- fused threshold + select (1 block, 1024 threads) ----------------
__global__ __launch_bounds__(1024) void rpn_threshsel(const u32* __restrict__ hist,
                                                      u32* __restrict__ info,
                                                      const u32* __restrict__ keys,
                                                      u64* __restrict__ selk) {
    __shared__ u32 tmp[1024];
    __shared__ u32 part[256], h2[256];
    __shared__ int segs;
    __shared__ u32 Tsh;
    const int t = threadIdx.x;
    {
        u32 s = 0;
        const u32* hp = hist + t * 64;
#pragma unroll 8
        for (int b = 0; b < 64; ++b) s += hp[b];
        tmp[t] = s;
    }
    __syncthreads();
    if (t < 256) part[t] = tmp[4 * t] + tmp[4 * t + 1] + tmp[4 * t + 2] + tmp[4 * t + 3];
    __syncthreads();
    for (int off = 1; off < 256; off <<= 1) {
        u32 v = 0, add = 0;
        if (t < 256) { v = part[t]; add = (t + off < 256) ? part[t + off] : 0u; }
        __syncthreads();
        if (t < 256) part[t] = v + add;
        __syncthreads();
    }
    if (t < 256) {
        u32 suf  = part[t];
        u32 sufn = (t < 255) ? part[t + 1] : 0u;
        if (suf >= NPRE && sufn < NPRE) segs = t;
    }
    __syncthreads();
    const int seg = segs;
    const u32 above = (seg < 255) ? part[seg + 1] : 0u;
    if (t < 256) h2[t] = hist[seg * 256 + t];
    __syncthreads();
    for (int off = 1; off < 256; off <<= 1) {
        u32 v = 0, add = 0;
        if (t < 256) { v = h2[t]; add = (t + off < 256) ? h2[t + off] : 0u; }
        __syncthreads();
        if (t < 256) h2[t] = v + add;
        __syncthreads();
    }
    if (t < 256) {
        u32 tot  = above + h2[t];
        u32 totn = above + ((t < 255) ? h2[t + 1] : 0u);
        if (tot >= NPRE && totn < NPRE) Tsh = (u32)(seg * 256 + t);
    }
    __syncthreads();
    const u32 T = Tsh;
    const int lane = t & 63;
    for (int base = 0; base < NANCH; base += 1024) {
        int idx = base + t;
        u32 k = (idx < NANCH) ? keys[idx] : 0u;
        bool sel = (idx < NANCH) && ((k >> 16) >= T);
        u64 ball = __ballot(sel);
        u32 wbase = 0;
        if (lane == 0 && ball) wbase = atomicAdd(&info[2], (u32)__popcll(ball));
        wbase = __shfl(wbase, 0);
        if (sel) {
            u32 pos = wbase + (u32)__popcll(ball & ((1ull << lane) - 1ull));
            if (pos < 8192) selk[pos] = ((u64)k << 32) | (u64)(0xFFFFFFFFu - (u32)idx);
        }
    }
}

// ---------------- multi-block bitonic sort (padded LDS, spread over CUs) ----------
__global__ __launch_bounds__(1024) void rpn_sort_local(u64* __restrict__ selk,
                                                       const u32* __restrict__ info) {
    __shared__ u64 s[2176];     // 2048 + 2048/16 pad
    const int t = threadIdx.x;
    const int seg = blockIdx.x;
    const int base = seg * 2048;
    int n = (int)info[2]; if (n > 8192) n = 8192;
    for (int i = t; i < 2048; i += 1024)
        s[PADL(i)] = (base + i < n) ? selk[base + i] : 0ull;
    __syncthreads();
    const bool D = ((seg & 1) == 0);
    for (int k = 2; k <= 2048; k <<= 1) {
        for (int j = k >> 1; j > 0; j >>= 1) {
            int p1 = ((t & ~(j - 1)) << 1) | (t & (j - 1));
            int p2 = p1 | j;
            bool desc = (((p1 & k) == 0) == D);
            u64 A = s[PADL(p1)], B = s[PADL(p2)];
            if (desc ? (A < B) : (A > B)) { s[PADL(p1)] = B; s[PADL(p2)] = A; }
            __syncthreads();
        }
    }
    for (int i = t; i < 2048; i += 1024) selk[base + i] = s[PADL(i)];
}

__global__ __launch_bounds__(512) void rpn_sort_gpass(u64* __restrict__ selk,
                                                      int k, int j) {
    int i = blockIdx.x * 512 + threadIdx.x;
    int p1 = ((i & ~(j - 1)) << 1) | (i & (j - 1));
    int p2 = p1 | j;
    bool desc = ((p1 & k) == 0);
    u64 A = selk[p1], B = selk[p2];
    if (desc ? (A < B) : (A > B)) { selk[p1] = B; selk[p2] = A; }
}

template <bool FINAL>
__global__ __launch_bounds__(1024) void rpn_sort_lmerge(u64* __restrict__ selk, int k,
                                                        const float* __restrict__ boxes,
                                                        float* __restrict__ bk) {
    __shared__ u64 s[2176];
    const int t = threadIdx.x;
    const int base = blockIdx.x * 2048;
    for (int i = t; i < 2048; i += 1024) s[PADL(i)] = selk[base + i];
    __syncthreads();
    const bool desc = ((base & k) == 0);
    for (int j = 1024; j > 0; j >>= 1) {
        int p1 = ((t & ~(j - 1)) << 1) | (t & (j - 1));
        int p2 = p1 | j;
        u64 A = s[PADL(p1)], B = s[PADL(p2)];
        if (desc ? (A < B) : (A > B)) { s[PADL(p1)] = B; s[PADL(p2)] = A; }
        __syncthreads();
    }
    if (FINAL) {
        for (int i = t; i < 2048; i += 1024) {
            int r = base + i;
            if (r < NPRE) {
                u32 oi = 0xFFFFFFFFu - (u32)(s[PADL(i)] & 0xFFFFFFFFull);
                if (oi >= NANCH) oi = 0;
                reinterpret_cast<float4*>(bk)[r] = reinterpret_cast<const float4*>(boxes)[oi];
            }
        }
    } else {
        for (int i = t; i < 2048; i += 1024) selk[base + i] = s[PADL(i)];
    }
}

// ---------------- IoU bitmask: 4 waves/block share the jb tile ----------------
__global__ __launch_bounds__(256) void rpn_iou(const float* __restrict__ bk,
                                               u64* __restrict__ mask) {
    const int t = threadIdx.x;
    const int lane = t & 63, w = t >> 6;
    const int bj = blockIdx.x;
    const int bi = blockIdx.y * 4 + w;       // grid.y = 24 -> bi 0..95 (guard < 94)
    const int j0 = bj * 64;
    __shared__ float4 jb[64];
    if (t < 64) jb[t] = (j0 + t < NPRE) ? reinterpret_cast<const float4*>(bk)[j0 + t]
                                        : make_float4(0.f, 0.f, 0.f, 0.f);
    __syncthreads();
    if (bi >= WPR) return;
    const int i = bi * 64 + lane;
    if (j0 + 63 <= bi * 64) {                // wave-uniform: all pairs j <= i
        if (i < NPRE) mask[(size_t)i * WPR + bj] = 0ull;
        return;
    }
    if (i >= NPRE) return;
    float4 b = reinterpret_cast<const float4*>(bk)[i];
    float areai = __fmul_rn(__fsub_rn(b.z, b.x), __fsub_rn(b.w, b.y));
    u64 bits = 0ull;
    for (int jj = 0; jj < 64; ++jj) {
        int j = j0 + jj;
        if (j <= i || j >= NPRE) continue;
        float4 c = jb[jj];
        float ty = fmaxf(b.x, c.x), tx = fmaxf(b.y, c.y);
        float by = fminf(b.z, c.z), bx2 = fminf(b.w, c.w);
        float ih = fmaxf(__fsub_rn(by, ty), 0.f);
        float iw = fmaxf(__fsub_rn(bx2, tx), 0.f);
        float inter = __fmul_rn(ih, iw);
        float areaj = __fmul_rn(__fsub_rn(c.z, c.x), __fsub_rn(c.w, c.y));
        float denom = __fadd_rn(__fsub_rn(__fadd_rn(areai, areaj), inter), 1e-9f);
        float iou = __fdiv_rn(inter, denom);
        if (iou > 0.7f) bits |= (1ull << jj);
    }
    mask[(size_t)i * WPR + bj] = bits;
}

// ---------------- sequential greedy NMS (single wave, 16-deep prefetch) ----------
__global__ __launch_bounds__(64) void rpn_nms(const u64* __restrict__ mask,
                                              const float* __restrict__ bk,
                                              float* __restrict__ rois) {
    const int lane = threadIdx.x;
    u64 rem0 = 0ull, rem1 = 0ull, curW = 0ull;
    __shared__ unsigned short klist[304];
    int kcnt = 0;
    u64 pm0[16], pm1[16], pmg[16];
#pragma unroll
    for (int u = 0; u < 16; ++u) {
        pm0[u] = mask[(size_t)u * WPR + lane];
        pm1[u] = (lane < 30) ? mask[(size_t)u * WPR + 64 + lane] : 0ull;
        pmg[u] = mask[(size_t)u * WPR + 0];
    }
    bool done = false;
    for (int base = 0; base < NPRE && !done; base += 16) {
        if ((base & 63) == 0) {
            int w = base >> 6;
            curW = (w < 64) ? __shfl(rem0, w) : __shfl(rem1, w - 64);
        }
#pragma unroll
        for (int u = 0; u < 16; ++u) {
            const int i = base + u;
            u64 m0 = pm0[u], m1 = pm1[u], mg = pmg[u];
            const int ni = i + 16;
            pm0[u] = mask[(size_t)ni * WPR + lane];
            pm1[u] = (lane < 30) ? mask[(size_t)ni * WPR + 64 + lane] : 0ull;
            pmg[u] = mask[(size_t)ni * WPR + (ni >> 6)];
            if (((curW >> (i & 63)) & 1ull) == 0ull) {
                rem0 |= m0;
                rem1 |= m1;
                curW |= mg;
                if (lane == 0 && kcnt < 304) klist[kcnt] = (unsigned short)i;
                ++kcnt;
                if (kcnt >= NPOST) { done = true; break; }
            }
        }
    }
    __syncthreads();
    const int nk = kcnt < NPOST ? kcnt : NPOST;
    for (int r = lane; r < nk; r += 64) {
        int bi = klist[r];
        reinterpret_cast<float4*>(rois)[r] = reinterpret_cast<const float4*>(bk)[bi];
    }
    if (kcnt < NPOST) {
        int pos = kcnt;
        for (int i = 0; i < NPRE && pos < NPOST; ++i) {
            int w = i >> 6;
            u64 wv = (w < 64) ? __shfl(rem0, w) : __shfl(rem1, w - 64);
            if ((wv >> (i & 63)) & 1ull) {
                if (lane < 4) rois[pos * 4 + lane] = bk[i * 4 + lane];
                ++pos;
            }
        }
    }
}

extern "C" void kernel_launch(void* const* d_in, const int* in_sizes, int n_in,
                              void* d_out, int out_size, void* d_ws, size_t ws_size,
                              hipStream_t stream) {
    (void)in_sizes; (void)n_in; (void)out_size;
    const float* feat = (const float*)d_in[0];
    const float* w1   = (const float*)d_in[1];
    const float* b1   = (const float*)d_in[2];
    const float* sw   = (const float*)d_in[3];
    const float* sb   = (const float*)d_in[4];
    const float* lw   = (const float*)d_in[5];
    const float* lb   = (const float*)d_in[6];
    const int*   ih   = (const int*)d_in[7];
    const int*   iw   = (const int*)d_in[8];
    float* out = (float*)d_out;

    const size_t WT_B    = 9437184;   // 512*512*9*4
    const size_t WT2_B   = 131072;    // 512*64*4
    const size_t REST_B  = WT2_B + 547200 + 136800 + 262144 + 64 + 65536 + 96000 + 4528128;
    const size_t SLICE_B = (size_t)512 * NPIX * 4;
    int nz; bool usewt;
    if      (ws_size >= 8 * SLICE_B + WT_B + REST_B) { nz = 8; usewt = true; }
    else if (ws_size >= 4 * SLICE_B + WT_B + REST_B) { nz = 4; usewt = true; }
    else if (ws_size >= 2 * SLICE_B + WT_B + REST_B) { nz = 2; usewt = true; }
    else                                             { nz = 2; usewt = false; }

    char* p = (char*)d_ws;
    float* Xpt = (float*)p;          p += (size_t)nz * SLICE_B;
    float* wt = nullptr;
    if (usewt) { wt = (float*)p;     p += WT_B; }
    float* wt2    = (float*)p;       p += WT2_B;
    float* boxes  = (float*)p;       p += 547200;
    u32*   keys   = (u32*)p;         p += 136800;
    u32*   hist   = (u32*)p;         p += 262144;
    u32*   info   = (u32*)p;         p += 64;
    u64*   selk   = (u64*)p;         p += 65536;
    float* bk     = (float*)p;       p += 96000;
    u64*   mask   = (u64*)p;

    const int cin_blk = 512 / nz;

    if (usewt) {
        rpn_wtrans<true><<<dim3(144, 16), 256, 0, stream>>>(w1, wt, sw, lw, wt2, hist, info);
        rpn_conv1<true><<<dim3(13, 8, nz), 256, 0, stream>>>(feat, wt, Xpt, cin_blk, 0);
    } else {
        rpn_wtrans<false><<<dim3(144, 16), 256, 0, stream>>>(w1, nullptr, sw, lw, wt2, hist, info);
        rpn_conv1<false><<<dim3(13, 8, nz), 256, 0, stream>>>(feat, w1, Xpt, cin_blk, 0);
    }
    rpn_head<<<475, 256, 0, stream>>>(Xpt, wt2, b1, sb, lb, ih, iw, out, boxes, keys, hist, nz);
    rpn_threshsel<<<1, 1024, 0, stream>>>(hist, info, keys, selk);
    rpn_sort_local<<<4, 1024, 0, stream>>>(selk, info);
    rpn_sort_gpass<<<8, 512, 0, stream>>>(selk, 4096, 2048);
    rpn_sort_lmerge<false><<<4, 1024, 0, stream>>>(selk, 4096, nullptr, nullptr);
    rpn_sort_gpass<<<8, 512, 0, stream>>>(selk, 8192, 4096);
    rpn_sort_gpass<<<8, 512, 0, stream>>>(selk, 8192, 2048);
    rpn_sort_lmerge<true><<<4, 1024, 0, stream>>>(selk, 8192, boxes, bk);
    rpn_iou<<<dim3(WPR, 24), 256, 0, stream>>>(bk, mask);
    rpn_nms<<<1, 64, 0, stream>>>(mask, bk, out + 205200);
}